// Round 1
// baseline (259.980 us; speedup 1.0000x reference)
//
#include <hip/hip_runtime.h>
#include <stdint.h>

#define N_B 2
#define T_SEQ 2048
#define D_MODEL 1024
#define N_HEADS 16
#define HEAD_W 64

typedef __attribute__((ext_vector_type(8))) short short8;
typedef __attribute__((ext_vector_type(4))) float f32x4;

// async global->LDS, 16B per lane; LDS dst must be wave-uniform base (HW adds lane*16)
#define GLOAD_LDS16(gp, lp)                                                          \
    __builtin_amdgcn_global_load_lds((__attribute__((address_space(1))) void*)(gp),  \
                                     (__attribute__((address_space(3))) void*)(lp),  \
                                     16, 0, 0)

__device__ __forceinline__ unsigned short f2bf(float f) {
    union { float f; uint32_t u; } c; c.f = f;
    return (unsigned short)((c.u + 0x7fffu + ((c.u >> 16) & 1u)) >> 16);  // RNE
}

// ---------------- f32 -> bf16 convert (vectorized, optional scale) ----------------
__global__ __launch_bounds__(256) void cvt_bf16(const float* __restrict__ src,
                                                unsigned short* __restrict__ dst,
                                                int n4, float scale) {
    int i = blockIdx.x * 256 + threadIdx.x;
    if (i >= n4) return;
    float4 v = ((const float4*)src)[i];
    union { unsigned short us[4]; uint64_t u64; } o;
    o.us[0] = f2bf(v.x * scale);
    o.us[1] = f2bf(v.y * scale);
    o.us[2] = f2bf(v.z * scale);
    o.us[3] = f2bf(v.w * scale);
    ((uint64_t*)dst)[i] = o.u64;
}

// ---------------- QKV projection GEMM: C[m,n] = sum_k A[m,k]*W[n,k] ----------------
// A: [4096,1024] bf16 (m = b*T + t), W: [1024,1024] bf16 (row n = output feature)
// mode 0: write bf16 at ((b*H+h)*T+t)*HW + w   (h = n>>6, w = n&63)   [Q, K]
// mode 1: write bf16 at ((b*H+h)*HW+w)*T + t   (V transposed for attention)
__global__ __launch_bounds__(256) void qkv_gemm(const unsigned short* __restrict__ A,
                                                const unsigned short* __restrict__ W,
                                                unsigned short* __restrict__ outp,
                                                int mode) {
    __shared__ unsigned short As[128 * 32];
    __shared__ unsigned short Ws[128 * 32];
    const int tid = threadIdx.x;
    const int lane = tid & 63;
    const int ww = tid >> 6;                // wave 0..3, 2x2 over the 128x128 tile
    const int m0 = blockIdx.y * 128;
    const int n0 = blockIdx.x * 128;
    const int wr = (ww >> 1) * 64;
    const int wc = (ww & 1) * 64;
    const int g8 = (lane >> 4) * 8;         // fragment k-offset
    const int fr = lane & 15;               // fragment row/col
    const int srow = lane >> 2;             // staging: 16 rows per 1KB chunk
    const int scol = (lane & 3) * 8;        // staging: 8 bf16 (16B) per lane

    f32x4 acc[4][4];
#pragma unroll
    for (int i = 0; i < 4; ++i)
#pragma unroll
        for (int j = 0; j < 4; ++j) acc[i][j] = (f32x4){0.f, 0.f, 0.f, 0.f};

    for (int k0 = 0; k0 < D_MODEL; k0 += 32) {
#pragma unroll
        for (int it = 0; it < 2; ++it) {
            const int chunk = ww * 2 + it;          // 0..7, each 16 rows x 32 bf16 = 1KB
            const int row = chunk * 16 + srow;      // 0..127
            GLOAD_LDS16(A + (size_t)(m0 + row) * D_MODEL + k0 + scol,
                        (unsigned short*)As + chunk * 512);
            GLOAD_LDS16(W + (size_t)(n0 + row) * D_MODEL + k0 + scol,
                        (unsigned short*)Ws + chunk * 512);
        }
        __syncthreads();   // drains vmcnt -> staged tiles visible
        short8 af[4], bf[4];
#pragma unroll
        for (int mi = 0; mi < 4; ++mi)
            af[mi] = *(const short8*)(As + (wr + mi * 16 + fr) * 32 + g8);
#pragma unroll
        for (int ni = 0; ni < 4; ++ni)
            bf[ni] = *(const short8*)(Ws + (wc + ni * 16 + fr) * 32 + g8);
#pragma unroll
        for (int mi = 0; mi < 4; ++mi)
#pragma unroll
            for (int ni = 0; ni < 4; ++ni)
                acc[mi][ni] = __builtin_amdgcn_mfma_f32_16x16x32_bf16(af[mi], bf[ni],
                                                                      acc[mi][ni], 0, 0, 0);
        __syncthreads();
    }

    const int ro = (lane >> 4) * 4;  // C-layout row base
#pragma unroll
    for (int mi = 0; mi < 4; ++mi) {
#pragma unroll
        for (int ni = 0; ni < 4; ++ni) {
#pragma unroll
            for (int r = 0; r < 4; ++r) {
                const int m = m0 + wr + mi * 16 + ro + r;
                const int n = n0 + wc + ni * 16 + fr;
                const int b = m >> 11, t = m & (T_SEQ - 1);
                const int h = n >> 6, wd = n & (HEAD_W - 1);
                size_t addr;
                if (mode == 0)
                    addr = ((size_t)(b * N_HEADS + h) * T_SEQ + t) * HEAD_W + wd;
                else
                    addr = ((size_t)(b * N_HEADS + h) * HEAD_W + wd) * T_SEQ + t;
                outp[addr] = f2bf(acc[mi][ni][r]);
            }
        }
    }
}

// ---------------- flash attention fwd, causal + ALiBi ----------------
// Q,K: bf16 [b,h,t,w] (Q pre-scaled by 1/8); Vt: bf16 [b,h,w,t]; out f32 [b,t,h*64+d]
__global__ __launch_bounds__(256) void attn_fwd(const unsigned short* __restrict__ Qb,
                                                const unsigned short* __restrict__ Kb,
                                                const unsigned short* __restrict__ Vtb,
                                                float* __restrict__ outp) {
    __shared__ unsigned short Klds[32 * 72];       // 32 kv-rows x 64 (+8 pad) bf16
    __shared__ unsigned short Vtlds[64 * 40];      // 64 d-rows x 32 (+8 pad) bf16
    __shared__ unsigned short Plds[4][16 * 40];    // per-wave P bounce, padded

    const int b = blockIdx.z, h = blockIdx.y;
    const int q0 = blockIdx.x * 64;
    const int tid = threadIdx.x;
    const int lane = tid & 63;
    const int w = tid >> 6;          // wave id, owns q rows [qw, qw+16)
    const int qw = q0 + w * 16;
    const float slope = exp2f(-0.5f * (float)(h + 1));

    const unsigned short* Qp = Qb + (size_t)(b * N_HEADS + h) * T_SEQ * HEAD_W;
    const unsigned short* Kp = Kb + (size_t)(b * N_HEADS + h) * T_SEQ * HEAD_W;
    const unsigned short* Vp = Vtb + (size_t)(b * N_HEADS + h) * HEAD_W * T_SEQ;

    const int g = lane >> 4;   // 0..3
    const int c = lane & 15;   // 0..15

    // Q fragments: a[j] = Q[qw + (lane&15)][(lane>>4)*8 + j + 32*kb]
    short8 qf[2];
#pragma unroll
    for (int kb = 0; kb < 2; ++kb)
        qf[kb] = *(const short8*)(Qp + (size_t)(qw + c) * HEAD_W + kb * 32 + g * 8);

    f32x4 o[4];
    float mrow[4], lrow[4];
#pragma unroll
    for (int i = 0; i < 4; ++i) {
        o[i] = (f32x4){0.f, 0.f, 0.f, 0.f};
        mrow[i] = -1e30f;
        lrow[i] = 0.f;
    }

    const int kv_end = q0 + 64;
    for (int k0 = 0; k0 < kv_end; k0 += 32) {
        // ---- stage K tile (32x64) and Vt tile (64x32), reg-staged for padding ----
        {
            const int jr = tid >> 3, c0 = (tid & 7) * 8;
            short8 kv = *(const short8*)(Kp + (size_t)(k0 + jr) * HEAD_W + c0);
            *(short8*)(Klds + jr * 72 + c0) = kv;
            const int dr = tid >> 2, j0 = (tid & 3) * 8;
            short8 vv = *(const short8*)(Vp + (size_t)dr * T_SEQ + k0 + j0);
            *(short8*)(Vtlds + dr * 40 + j0) = vv;
        }
        __syncthreads();

        if (k0 <= qw + 15) {   // wave-uniform: skip fully-masked tiles
            // ---- S = Q K^T (already scaled), two 16x16 tiles ----
            f32x4 s[2];
#pragma unroll
            for (int ct = 0; ct < 2; ++ct) {
                f32x4 a = (f32x4){0.f, 0.f, 0.f, 0.f};
#pragma unroll
                for (int kb = 0; kb < 2; ++kb) {
                    short8 kf = *(const short8*)(Klds + (ct * 16 + c) * 72 + kb * 32 + g * 8);
                    a = __builtin_amdgcn_mfma_f32_16x16x32_bf16(qf[kb], kf, a, 0, 0, 0);
                }
                s[ct] = a;
            }
            // ---- ALiBi + causal mask, online softmax update ----
            float sc[4], p0[4], p1[4];
#pragma unroll
            for (int r = 0; r < 4; ++r) {
                const int i = qw + g * 4 + r;        // query row
                const int ja = k0 + c, jb = ja + 16; // key cols
                float s0 = (ja <= i) ? s[0][r] + slope * (float)(ja - i) : -1e30f;
                float s1 = (jb <= i) ? s[1][r] + slope * (float)(jb - i) : -1e30f;
                float tm = fmaxf(s0, s1);
                tm = fmaxf(tm, __shfl_xor(tm, 1));
                tm = fmaxf(tm, __shfl_xor(tm, 2));
                tm = fmaxf(tm, __shfl_xor(tm, 4));
                tm = fmaxf(tm, __shfl_xor(tm, 8));
                const float mnew = fmaxf(mrow[r], tm);
                sc[r] = __expf(mrow[r] - mnew);
                p0[r] = __expf(s0 - mnew);
                p1[r] = __expf(s1 - mnew);
                float ts = p0[r] + p1[r];
                ts += __shfl_xor(ts, 1);
                ts += __shfl_xor(ts, 2);
                ts += __shfl_xor(ts, 4);
                ts += __shfl_xor(ts, 8);
                lrow[r] = lrow[r] * sc[r] + ts;
                mrow[r] = mnew;
            }
#pragma unroll
            for (int db = 0; db < 4; ++db)
#pragma unroll
                for (int r = 0; r < 4; ++r) o[db][r] *= sc[r];

            // ---- P (C-layout) -> LDS -> A-fragment layout (same-wave, DS in-order) ----
#pragma unroll
            for (int r = 0; r < 4; ++r) {
                Plds[w][(g * 4 + r) * 40 + c]      = f2bf(p0[r]);
                Plds[w][(g * 4 + r) * 40 + 16 + c] = f2bf(p1[r]);
            }
            short8 pa = *(const short8*)(&Plds[w][c * 40 + g * 8]);
            // ---- O += P V : B-frag b[j] = V[(lane>>4)*8+j][db*16 + (lane&15)] ----
#pragma unroll
            for (int db = 0; db < 4; ++db) {
                short8 vf = *(const short8*)(Vtlds + (db * 16 + c) * 40 + g * 8);
                o[db] = __builtin_amdgcn_mfma_f32_16x16x32_bf16(pa, vf, o[db], 0, 0, 0);
            }
        }
        __syncthreads();
    }

    // ---- epilogue: out[b][t][h*64+d] = o / l ----
#pragma unroll
    for (int db = 0; db < 4; ++db) {
#pragma unroll
        for (int r = 0; r < 4; ++r) {
            const int tq = qw + g * 4 + r;
            const int d = db * 16 + c;
            outp[((size_t)b * T_SEQ + tq) * D_MODEL + h * HEAD_W + d] = o[db][r] / lrow[r];
        }
    }
}

// ---------------- launch ----------------
extern "C" void kernel_launch(void* const* d_in, const int* in_sizes, int n_in,
                              void* d_out, int out_size, void* d_ws, size_t ws_size,
                              hipStream_t stream) {
    const float* x  = (const float*)d_in[0];
    // d_in[1] = additive causal mask, applied analytically -> unused
    const float* Wq = (const float*)d_in[2];
    const float* Wk = (const float*)d_in[3];
    const float* Wv = (const float*)d_in[4];
    float* out = (float*)d_out;

    uint8_t* ws = (uint8_t*)d_ws;
    unsigned short* xb  = (unsigned short*)(ws);              // 8 MB   x bf16 [4096,1024]
    unsigned short* wqb = (unsigned short*)(ws + 8388608);    // 2 MB   Wq/8 bf16
    unsigned short* wkb = (unsigned short*)(ws + 10485760);   // 2 MB
    unsigned short* wvb = (unsigned short*)(ws + 12582912);   // 2 MB
    unsigned short* Qb  = (unsigned short*)(ws + 14680064);   // 8 MB   [b,h,t,w]
    unsigned short* Kb  = (unsigned short*)(ws + 23068672);   // 8 MB   [b,h,t,w]
    unsigned short* Vtb = (unsigned short*)(ws + 31457280);   // 8 MB   [b,h,w,t]

    cvt_bf16<<<4096, 256, 0, stream>>>(x,  xb,  (N_B * T_SEQ * D_MODEL) / 4, 1.0f);
    cvt_bf16<<<1024, 256, 0, stream>>>(Wq, wqb, (D_MODEL * D_MODEL) / 4, 0.125f); // fold 1/sqrt(HW)
    cvt_bf16<<<1024, 256, 0, stream>>>(Wk, wkb, (D_MODEL * D_MODEL) / 4, 1.0f);
    cvt_bf16<<<1024, 256, 0, stream>>>(Wv, wvb, (D_MODEL * D_MODEL) / 4, 1.0f);

    dim3 gg(D_MODEL / 128, (N_B * T_SEQ) / 128);   // (8, 32)
    qkv_gemm<<<gg, 256, 0, stream>>>(xb, wqb, Qb, 0);
    qkv_gemm<<<gg, 256, 0, stream>>>(xb, wkb, Kb, 0);
    qkv_gemm<<<gg, 256, 0, stream>>>(xb, wvb, Vtb, 1);

    dim3 ga(T_SEQ / 64, N_HEADS, N_B);             // (32, 16, 2)
    attn_fwd<<<ga, 256, 0, stream>>>(Qb, Kb, Vtb, out);
}

// Round 2
// 196.385 us; speedup vs baseline: 1.3238x; 1.3238x over previous
//
#include <hip/hip_runtime.h>
#include <stdint.h>

#define N_B 2
#define T_SEQ 2048
#define D_MODEL 1024
#define N_HEADS 16
#define HEAD_W 64

typedef __attribute__((ext_vector_type(8))) short short8;
typedef __attribute__((ext_vector_type(4))) float f32x4;

// async global->LDS, 16B per lane; LDS dst is wave-uniform base (HW adds lane*16)
#define GLOAD_LDS16(gp, lp)                                                          \
    __builtin_amdgcn_global_load_lds((__attribute__((address_space(1))) void*)(gp),  \
                                     (__attribute__((address_space(3))) void*)(lp),  \
                                     16, 0, 0)

__device__ __forceinline__ unsigned short f2bf(float f) {
    union { float f; uint32_t u; } cv; cv.f = f;
    return (unsigned short)((cv.u + 0x7fffu + ((cv.u >> 16) & 1u)) >> 16);  // RNE
}

#define LOG2E 1.44269504f

// ---------------- fused f32 -> bf16 converts (x, Wq*scale, Wk, Wv) ----------------
__global__ __launch_bounds__(256) void cvt_fused(const float4* __restrict__ x,
                                                 const float4* __restrict__ wq,
                                                 const float4* __restrict__ wk,
                                                 const float4* __restrict__ wv,
                                                 uint64_t* __restrict__ xb,
                                                 uint64_t* __restrict__ wqb,
                                                 uint64_t* __restrict__ wkb,
                                                 uint64_t* __restrict__ wvb) {
    const int i = blockIdx.x * 256 + threadIdx.x;   // 1835008 total float4s
    const float4* src; uint64_t* dst; float scale; int off;
    if (i < 1048576)      { src = x;  dst = xb;  scale = 1.f;            off = i; }
    else if (i < 1310720) { src = wq; dst = wqb; scale = 0.125f * LOG2E; off = i - 1048576; }
    else if (i < 1572864) { src = wk; dst = wkb; scale = 1.f;            off = i - 1310720; }
    else                  { src = wv; dst = wvb; scale = 1.f;            off = i - 1572864; }
    float4 v = src[off];
    union { unsigned short us[4]; uint64_t u64; } o;
    o.us[0] = f2bf(v.x * scale);
    o.us[1] = f2bf(v.y * scale);
    o.us[2] = f2bf(v.z * scale);
    o.us[3] = f2bf(v.w * scale);
    dst[off] = o.u64;
}

// ---------------- QKV projection GEMM (z-fused): C[m,n] = sum_k A[m,k]*W[n,k] ----------------
// z=0: Q -> [b,h,t,w]; z=1: K -> [b,h,t,w]; z=2: V -> [b,h,w,t] (transposed via LDS bounce)
__global__ __launch_bounds__(256) void qkv_gemm(const unsigned short* __restrict__ A,
                                                const unsigned short* __restrict__ W0,
                                                const unsigned short* __restrict__ W1,
                                                const unsigned short* __restrict__ W2,
                                                unsigned short* __restrict__ O0,
                                                unsigned short* __restrict__ O1,
                                                unsigned short* __restrict__ O2) {
    __shared__ union {
        struct { unsigned short A[128 * 32]; unsigned short W[128 * 32]; } st;
        unsigned short vb[4][64 * 72];   // V transpose bounce (padded rows, 144B)
    } sh;
    const int z = blockIdx.z;
    const unsigned short* W = (z == 0) ? W0 : (z == 1) ? W1 : W2;
    const int tid = threadIdx.x;
    const int lane = tid & 63;
    const int ww = tid >> 6;
    const int m0 = blockIdx.y * 128;
    const int n0 = blockIdx.x * 128;
    const int wr = (ww >> 1) * 64;
    const int wc = (ww & 1) * 64;
    const int g = lane >> 4;             // k-granule 0..3 (8 bf16 each)
    const int fr = lane & 15;
    const int srow = lane >> 2;          // staging row-in-chunk 0..15
    const int sgr = (lane & 3) ^ (srow & 3);   // pre-swizzled source granule

    f32x4 acc[4][4];
#pragma unroll
    for (int i = 0; i < 4; ++i)
#pragma unroll
        for (int j = 0; j < 4; ++j) acc[i][j] = (f32x4){0.f, 0.f, 0.f, 0.f};

    for (int k0 = 0; k0 < D_MODEL; k0 += 32) {
#pragma unroll
        for (int it = 0; it < 2; ++it) {
            const int chunk = ww * 2 + it;
            const int row = chunk * 16 + srow;
            GLOAD_LDS16(A + (size_t)(m0 + row) * D_MODEL + k0 + sgr * 8,
                        (unsigned short*)sh.st.A + chunk * 512);
            GLOAD_LDS16(W + (size_t)(n0 + row) * D_MODEL + k0 + sgr * 8,
                        (unsigned short*)sh.st.W + chunk * 512);
        }
        __syncthreads();
        short8 af[4], bf[4];
#pragma unroll
        for (int mi = 0; mi < 4; ++mi) {
            const int row = wr + mi * 16 + fr;
            af[mi] = *(const short8*)(sh.st.A + row * 32 + ((g ^ (fr & 3)) * 8));
        }
#pragma unroll
        for (int ni = 0; ni < 4; ++ni) {
            const int row = wc + ni * 16 + fr;
            bf[ni] = *(const short8*)(sh.st.W + row * 32 + ((g ^ (fr & 3)) * 8));
        }
#pragma unroll
        for (int mi = 0; mi < 4; ++mi)
#pragma unroll
            for (int ni = 0; ni < 4; ++ni)
                acc[mi][ni] = __builtin_amdgcn_mfma_f32_16x16x32_bf16(af[mi], bf[ni],
                                                                      acc[mi][ni], 0, 0, 0);
        __syncthreads();
    }

    const int ro = g * 4;   // C-layout row base
    if (z < 2) {
        unsigned short* outp = (z == 0) ? O0 : O1;
#pragma unroll
        for (int mi = 0; mi < 4; ++mi) {
#pragma unroll
            for (int ni = 0; ni < 4; ++ni) {
#pragma unroll
                for (int r = 0; r < 4; ++r) {
                    const int m = m0 + wr + mi * 16 + ro + r;
                    const int n = n0 + wc + ni * 16 + fr;
                    const int b = m >> 11, t = m & (T_SEQ - 1);
                    const int h = n >> 6, wd = n & (HEAD_W - 1);
                    outp[((size_t)(b * N_HEADS + h) * T_SEQ + t) * HEAD_W + wd] =
                        f2bf(acc[mi][ni][r]);
                }
            }
        }
    } else {
        // V: transpose through per-wave LDS bounce, coalesced 16B stores
#pragma unroll
        for (int mi = 0; mi < 4; ++mi)
#pragma unroll
            for (int ni = 0; ni < 4; ++ni)
#pragma unroll
                for (int r = 0; r < 4; ++r)
                    sh.vb[ww][(ni * 16 + fr) * 72 + mi * 16 + ro + r] = f2bf(acc[mi][ni][r]);
        // same-wave buffer: DS in-order, no barrier needed
#pragma unroll
        for (int rep = 0; rep < 8; ++rep) {
            const int nl = rep * 8 + (lane >> 3);          // row within wave quadrant (n)
            const int n = n0 + wc + nl;
            const int h = n >> 6, wd = n & (HEAD_W - 1);
            const int m = m0 + wr + (lane & 7) * 8;        // 8 consecutive t
            const int b = m >> 11, t = m & (T_SEQ - 1);
            short8 vv = *(const short8*)(&sh.vb[ww][nl * 72 + (lane & 7) * 8]);
            *(short8*)(O2 + ((size_t)(b * N_HEADS + h) * HEAD_W + wd) * T_SEQ + t) = vv;
        }
    }
}

// ---------------- flash attention fwd, causal + ALiBi ----------------
// Q,K: bf16 [b,h,t,w] (Q pre-scaled by log2e/8); Vt: bf16 [b,h,w,t]; out f32 [b,t,h*64+d]
// 4 waves x 32 q-rows = 128 q/block; KV tile 64, double-buffered swizzled LDS staging.
__global__ __launch_bounds__(256) void attn_fwd(const unsigned short* __restrict__ Qb,
                                                const unsigned short* __restrict__ Kb,
                                                const unsigned short* __restrict__ Vtb,
                                                float* __restrict__ outp) {
    __shared__ unsigned short Kl[2][64 * 64];    // swizzled: granule ^= row&7
    __shared__ unsigned short Vl[2][64 * 64];    // swizzled: granule ^= d&7
    __shared__ unsigned short Pl[4][16 * 72];    // per-wave P bounce, 144B rows

    const int b = blockIdx.z, h = blockIdx.y;
    const int qi = (b == 1) ? (15 - blockIdx.x) : blockIdx.x;  // heavy+light pairing
    const int q0 = qi * 128;
    const int tid = threadIdx.x;
    const int lane = tid & 63;
    const int w = tid >> 6;
    const int qw = q0 + w * 32;
    const float slope2 = exp2f(-0.5f * (float)(h + 1)) * LOG2E;

    const unsigned short* Qp = Qb + (size_t)(b * N_HEADS + h) * T_SEQ * HEAD_W;
    const unsigned short* Kp = Kb + (size_t)(b * N_HEADS + h) * T_SEQ * HEAD_W;
    const unsigned short* Vp = Vtb + (size_t)(b * N_HEADS + h) * HEAD_W * T_SEQ;

    const int g = lane >> 4, c = lane & 15;
    const int srow = lane >> 3;                 // staging row-in-chunk 0..7
    const int sgr = (lane & 7) ^ (srow & 7);    // pre-swizzled source granule

#define STAGE_KV(buf, k0_)                                                               \
    {                                                                                    \
        _Pragma("unroll")                                                                \
        for (int it = 0; it < 2; ++it) {                                                 \
            const int ch = w * 2 + it;                                                   \
            const int row = ch * 8 + srow;                                               \
            GLOAD_LDS16(Kp + (size_t)((k0_) + row) * HEAD_W + sgr * 8,                   \
                        (unsigned short*)Kl[buf] + ch * 512);                            \
            GLOAD_LDS16(Vp + (size_t)row * T_SEQ + (k0_) + sgr * 8,                      \
                        (unsigned short*)Vl[buf] + ch * 512);                            \
        }                                                                                \
    }

    short8 qf[2][2];
#pragma unroll
    for (int qt = 0; qt < 2; ++qt)
#pragma unroll
        for (int kb = 0; kb < 2; ++kb)
            qf[qt][kb] = *(const short8*)(Qp + (size_t)(qw + qt * 16 + c) * HEAD_W +
                                          kb * 32 + g * 8);

    f32x4 o[2][4];
    float mrow[2][4], lrow[2][4];
#pragma unroll
    for (int qt = 0; qt < 2; ++qt)
#pragma unroll
        for (int i = 0; i < 4; ++i) {
            o[qt][i] = (f32x4){0.f, 0.f, 0.f, 0.f};
            mrow[qt][i] = -1e30f;
            lrow[qt][i] = 0.f;
        }

    const int nt = q0 / 64 + 2;
    STAGE_KV(0, 0);
    __syncthreads();

    for (int t = 0; t < nt; ++t) {
        const int k0 = t * 64;
        if (t + 1 < nt) STAGE_KV((t + 1) & 1, k0 + 64);   // overlaps with compute below
        const unsigned short* Kt = Kl[t & 1];
        const unsigned short* Vt = Vl[t & 1];

#pragma unroll
        for (int qt = 0; qt < 2; ++qt) {
            const int qb0 = qw + qt * 16;
            if (k0 > qb0 + 15) continue;            // wave-uniform: fully masked
            const bool full = (k0 + 63 <= qb0);     // no causal masking needed

            // ---- S = Q K^T (log2e-scaled) ----
            f32x4 s[4];
#pragma unroll
            for (int ct = 0; ct < 4; ++ct) s[ct] = (f32x4){0.f, 0.f, 0.f, 0.f};
#pragma unroll
            for (int ct = 0; ct < 4; ++ct)
#pragma unroll
                for (int kb = 0; kb < 2; ++kb) {
                    const short8 kf = *(const short8*)(Kt + (ct * 16 + c) * 64 +
                                                       (((kb * 4 + g) ^ (c & 7)) * 8));
                    s[ct] = __builtin_amdgcn_mfma_f32_16x16x32_bf16(qf[qt][kb], kf, s[ct],
                                                                    0, 0, 0);
                }

            // ---- ALiBi + causal mask + online softmax (exp2 domain) ----
            float sc[4];
#pragma unroll
            for (int r = 0; r < 4; ++r) {
                const int i = qb0 + g * 4 + r;
                float sv[4];
                if (full) {
#pragma unroll
                    for (int ct = 0; ct < 4; ++ct)
                        sv[ct] = s[ct][r] + slope2 * (float)(k0 + ct * 16 + c - i);
                } else {
#pragma unroll
                    for (int ct = 0; ct < 4; ++ct) {
                        const int j = k0 + ct * 16 + c;
                        sv[ct] = (j <= i) ? s[ct][r] + slope2 * (float)(j - i) : -1e30f;
                    }
                }
                float tm = fmaxf(fmaxf(sv[0], sv[1]), fmaxf(sv[2], sv[3]));
                tm = fmaxf(tm, __shfl_xor(tm, 1));
                tm = fmaxf(tm, __shfl_xor(tm, 2));
                tm = fmaxf(tm, __shfl_xor(tm, 4));
                tm = fmaxf(tm, __shfl_xor(tm, 8));
                const float mnew = fmaxf(mrow[qt][r], tm);
                sc[r] = exp2f(mrow[qt][r] - mnew);
                mrow[qt][r] = mnew;
                float ts = 0.f;
#pragma unroll
                for (int ct = 0; ct < 4; ++ct) {
                    const float p = exp2f(sv[ct] - mnew);
                    Pl[w][(g * 4 + r) * 72 + ct * 16 + c] = f2bf(p);
                    ts += p;
                }
                ts += __shfl_xor(ts, 1);
                ts += __shfl_xor(ts, 2);
                ts += __shfl_xor(ts, 4);
                ts += __shfl_xor(ts, 8);
                lrow[qt][r] = lrow[qt][r] * sc[r] + ts;
            }
#pragma unroll
            for (int db = 0; db < 4; ++db)
#pragma unroll
                for (int r = 0; r < 4; ++r) o[qt][db][r] *= sc[r];

            // ---- O += P V (P via same-wave LDS bounce into A-fragment layout) ----
            short8 pa[2];
#pragma unroll
            for (int ks = 0; ks < 2; ++ks)
                pa[ks] = *(const short8*)(&Pl[w][c * 72 + ks * 32 + g * 8]);
#pragma unroll
            for (int db = 0; db < 4; ++db)
#pragma unroll
                for (int ks = 0; ks < 2; ++ks) {
                    const short8 vf = *(const short8*)(Vt + (db * 16 + c) * 64 +
                                                       (((ks * 4 + g) ^ (c & 7)) * 8));
                    o[qt][db] = __builtin_amdgcn_mfma_f32_16x16x32_bf16(pa[ks], vf,
                                                                        o[qt][db], 0, 0, 0);
                }
        }
        __syncthreads();   // drains next-tile staging (vmcnt) + this-tile LDS reads
    }

    // ---- epilogue ----
#pragma unroll
    for (int qt = 0; qt < 2; ++qt)
#pragma unroll
        for (int r = 0; r < 4; ++r) {
            const float rl = 1.0f / lrow[qt][r];
            const int tq = qw + qt * 16 + g * 4 + r;
#pragma unroll
            for (int db = 0; db < 4; ++db)
                outp[((size_t)b * T_SEQ + tq) * D_MODEL + h * HEAD_W + db * 16 + c] =
                    o[qt][db][r] * rl;
        }
#undef STAGE_KV
}

// ---------------- launch ----------------
extern "C" void kernel_launch(void* const* d_in, const int* in_sizes, int n_in,
                              void* d_out, int out_size, void* d_ws, size_t ws_size,
                              hipStream_t stream) {
    const float* x  = (const float*)d_in[0];
    // d_in[1] = additive causal mask, applied analytically -> unused
    const float* Wq = (const float*)d_in[2];
    const float* Wk = (const float*)d_in[3];
    const float* Wv = (const float*)d_in[4];
    float* out = (float*)d_out;

    uint8_t* ws = (uint8_t*)d_ws;
    unsigned short* xb  = (unsigned short*)(ws);              // 8 MB  x bf16 [4096,1024]
    unsigned short* wqb = (unsigned short*)(ws + 8388608);    // 2 MB  Wq * (log2e/8)
    unsigned short* wkb = (unsigned short*)(ws + 10485760);   // 2 MB
    unsigned short* wvb = (unsigned short*)(ws + 12582912);   // 2 MB
    unsigned short* Qb  = (unsigned short*)(ws + 14680064);   // 8 MB  [b,h,t,w]
    unsigned short* Kb  = (unsigned short*)(ws + 23068672);   // 8 MB  [b,h,t,w]
    unsigned short* Vtb = (unsigned short*)(ws + 31457280);   // 8 MB  [b,h,w,t]

    cvt_fused<<<7168, 256, 0, stream>>>((const float4*)x, (const float4*)Wq,
                                        (const float4*)Wk, (const float4*)Wv,
                                        (uint64_t*)xb, (uint64_t*)wqb,
                                        (uint64_t*)wkb, (uint64_t*)wvb);

    dim3 gg(D_MODEL / 128, (N_B * T_SEQ) / 128, 3);   // (8, 32, 3)
    qkv_gemm<<<gg, 256, 0, stream>>>(xb, wqb, wkb, wvb, Qb, Kb, Vtb);

    dim3 ga(T_SEQ / 128, N_HEADS, N_B);               // (16, 16, 2)
    attn_fwd<<<ga, 256, 0, stream>>>(Qb, Kb, Vtb, out);
}

// Round 3
// 104.691 us; speedup vs baseline: 2.4833x; 1.8759x over previous
//
#include <hip/hip_runtime.h>
#include <stdint.h>

#define N_B 2
#define T_SEQ 2048
#define D_MODEL 1024
#define N_HEADS 16
#define HEAD_W 64

typedef __attribute__((ext_vector_type(8))) short short8;
typedef __attribute__((ext_vector_type(4))) float f32x4;

// async global->LDS, 16B per lane; LDS dst is wave-uniform base (HW adds lane*16)
#define GLOAD_LDS16(gp, lp)                                                          \
    __builtin_amdgcn_global_load_lds((__attribute__((address_space(1))) void*)(gp),  \
                                     (__attribute__((address_space(3))) void*)(lp),  \
                                     16, 0, 0)

__device__ __forceinline__ unsigned short f2bf(float f) {
    union { float f; uint32_t u; } cv; cv.f = f;
    return (unsigned short)((cv.u + 0x7fffu + ((cv.u >> 16) & 1u)) >> 16);  // RNE
}

__device__ __forceinline__ uint32_t cvt_pk_bf16(float lo, float hi) {
    uint32_t r;
    asm("v_cvt_pk_bf16_f32 %0, %1, %2" : "=v"(r) : "v"(lo), "v"(hi));
    return r;
}

#define LOG2E 1.44269504f

// ---------------- fused f32 -> bf16 converts (x, Wq*scale, Wk, Wv) ----------------
__global__ __launch_bounds__(256) void cvt_fused(const float4* __restrict__ x,
                                                 const float4* __restrict__ wq,
                                                 const float4* __restrict__ wk,
                                                 const float4* __restrict__ wv,
                                                 uint64_t* __restrict__ xb,
                                                 uint64_t* __restrict__ wqb,
                                                 uint64_t* __restrict__ wkb,
                                                 uint64_t* __restrict__ wvb) {
    const int i = blockIdx.x * 256 + threadIdx.x;   // 1835008 total float4s
    const float4* src; uint64_t* dst; float scale; int off;
    if (i < 1048576)      { src = x;  dst = xb;  scale = 1.f;            off = i; }
    else if (i < 1310720) { src = wq; dst = wqb; scale = 0.125f * LOG2E; off = i - 1048576; }
    else if (i < 1572864) { src = wk; dst = wkb; scale = 1.f;            off = i - 1310720; }
    else                  { src = wv; dst = wvb; scale = 1.f;            off = i - 1572864; }
    float4 v = src[off];
    union { unsigned short us[4]; uint64_t u64; } o;
    o.us[0] = f2bf(v.x * scale);
    o.us[1] = f2bf(v.y * scale);
    o.us[2] = f2bf(v.z * scale);
    o.us[3] = f2bf(v.w * scale);
    dst[off] = o.u64;
}

// ---------------- QKV projection GEMM (z-fused, BK=64): C[m,n] = sum_k A[m,k]*W[n,k] ----------
// z=0: Q -> [b,h,t,w]; z=1: K -> [b,h,t,w]; z=2: V -> [b,h,w,t] (transposed via LDS bounce)
__global__ __launch_bounds__(256) void qkv_gemm(const unsigned short* __restrict__ A,
                                                const unsigned short* __restrict__ W0,
                                                const unsigned short* __restrict__ W1,
                                                const unsigned short* __restrict__ W2,
                                                unsigned short* __restrict__ O0,
                                                unsigned short* __restrict__ O1,
                                                unsigned short* __restrict__ O2) {
    __shared__ union {
        struct { unsigned short A[128 * 64]; unsigned short W[128 * 64]; } st;
        unsigned short vb[4][64 * 72];   // V transpose bounce (padded rows, 144B)
    } sh;
    const int z = blockIdx.z;
    const unsigned short* W = (z == 0) ? W0 : (z == 1) ? W1 : W2;
    const int tid = threadIdx.x;
    const int lane = tid & 63;
    const int ww = tid >> 6;
    const int m0 = blockIdx.y * 128;
    const int n0 = blockIdx.x * 128;
    const int wr = (ww >> 1) * 64;
    const int wc = (ww & 1) * 64;
    const int g = lane >> 4;             // k-granule 0..3 within 32-k chunk
    const int fr = lane & 15;
    const int srow = lane >> 3;          // staging row-in-chunk 0..7 (8 rows x 128B per 1KB)
    const int sgr = (lane & 7) ^ srow;   // pre-swizzled source granule (granule ^= row&7)

    f32x4 acc[4][4];
#pragma unroll
    for (int i = 0; i < 4; ++i)
#pragma unroll
        for (int j = 0; j < 4; ++j) acc[i][j] = (f32x4){0.f, 0.f, 0.f, 0.f};

    for (int k0 = 0; k0 < D_MODEL; k0 += 64) {
#pragma unroll
        for (int it = 0; it < 4; ++it) {
            const int chunk = ww * 4 + it;          // 0..15, each 8 rows x 64 shorts
            const int row = chunk * 8 + srow;       // 0..127
            GLOAD_LDS16(A + (size_t)(m0 + row) * D_MODEL + k0 + sgr * 8,
                        (unsigned short*)sh.st.A + chunk * 512);
            GLOAD_LDS16(W + (size_t)(n0 + row) * D_MODEL + k0 + sgr * 8,
                        (unsigned short*)sh.st.W + chunk * 512);
        }
        __syncthreads();
#pragma unroll
        for (int kb = 0; kb < 2; ++kb) {
            short8 af[4], bf[4];
#pragma unroll
            for (int mi = 0; mi < 4; ++mi) {
                const int row = wr + mi * 16 + fr;
                af[mi] = *(const short8*)(sh.st.A + row * 64 +
                                          (((kb * 4 + g) ^ (fr & 7)) * 8));
            }
#pragma unroll
            for (int ni = 0; ni < 4; ++ni) {
                const int row = wc + ni * 16 + fr;
                bf[ni] = *(const short8*)(sh.st.W + row * 64 +
                                          (((kb * 4 + g) ^ (fr & 7)) * 8));
            }
#pragma unroll
            for (int mi = 0; mi < 4; ++mi)
#pragma unroll
                for (int ni = 0; ni < 4; ++ni)
                    acc[mi][ni] = __builtin_amdgcn_mfma_f32_16x16x32_bf16(af[mi], bf[ni],
                                                                          acc[mi][ni], 0, 0, 0);
        }
        __syncthreads();
    }

    const int ro = g * 4;   // C-layout row base
    if (z < 2) {
        unsigned short* outp = (z == 0) ? O0 : O1;
#pragma unroll
        for (int mi = 0; mi < 4; ++mi) {
#pragma unroll
            for (int ni = 0; ni < 4; ++ni) {
#pragma unroll
                for (int r = 0; r < 4; ++r) {
                    const int m = m0 + wr + mi * 16 + ro + r;
                    const int n = n0 + wc + ni * 16 + fr;
                    const int b = m >> 11, t = m & (T_SEQ - 1);
                    const int h = n >> 6, wd = n & (HEAD_W - 1);
                    outp[((size_t)(b * N_HEADS + h) * T_SEQ + t) * HEAD_W + wd] =
                        f2bf(acc[mi][ni][r]);
                }
            }
        }
    } else {
        // V: transpose through per-wave LDS bounce, coalesced 16B stores
#pragma unroll
        for (int mi = 0; mi < 4; ++mi)
#pragma unroll
            for (int ni = 0; ni < 4; ++ni)
#pragma unroll
                for (int r = 0; r < 4; ++r)
                    sh.vb[ww][(ni * 16 + fr) * 72 + mi * 16 + ro + r] = f2bf(acc[mi][ni][r]);
        // same-wave buffer: DS in-order, no barrier needed
#pragma unroll
        for (int rep = 0; rep < 8; ++rep) {
            const int nl = rep * 8 + (lane >> 3);          // row within wave quadrant (n)
            const int n = n0 + wc + nl;
            const int h = n >> 6, wd = n & (HEAD_W - 1);
            const int m = m0 + wr + (lane & 7) * 8;        // 8 consecutive t
            const int b = m >> 11, t = m & (T_SEQ - 1);
            short8 vv = *(const short8*)(&sh.vb[ww][nl * 72 + (lane & 7) * 8]);
            *(short8*)(O2 + ((size_t)(b * N_HEADS + h) * HEAD_W + wd) * T_SEQ + t) = vv;
        }
    }
}

// ---------------- flash attention fwd, causal + ALiBi, swapped-QK^T in-register softmax ----
// Q,K: bf16 [b,h,t,w] (Q pre-scaled by log2e/8); Vt: bf16 [b,h,w,t]; out f32 [b,t,h*64+d]
// 4 waves x 16 q-rows = 64 q/block; KV tile 64, dbuf swizzled LDS; descending k + defer-max.
__global__ __launch_bounds__(256, 4) void attn_fwd(const unsigned short* __restrict__ Qb,
                                                   const unsigned short* __restrict__ Kb,
                                                   const unsigned short* __restrict__ Vtb,
                                                   float* __restrict__ outp) {
    __shared__ unsigned short Kl[2][64 * 64];    // [kv-row][d], granule ^= row&7
    __shared__ unsigned short Vl[2][64 * 64];    // [d][kv],   granule ^= d&7

    const int bid = blockIdx.x;                  // 1024 blocks, heavy-first LPT order
    const int qi = 31 - (bid >> 5);
    const int bh = bid & 31;                     // same bh -> same XCD (bid%8 == bh%8)
    const int b = bh >> 4, h = bh & 15;
    const int q0 = qi * 64;
    const int tid = threadIdx.x, lane = tid & 63, w = tid >> 6;
    const int qw = q0 + w * 16;
    const float slope2 = exp2f(-0.5f * (float)(h + 1)) * LOG2E;

    const unsigned short* Qp = Qb + (size_t)(b * N_HEADS + h) * T_SEQ * HEAD_W;
    const unsigned short* Kp = Kb + (size_t)(b * N_HEADS + h) * T_SEQ * HEAD_W;
    const unsigned short* Vp = Vtb + (size_t)(b * N_HEADS + h) * HEAD_W * T_SEQ;

    const int g = lane >> 4, c = lane & 15;
    const int srow = lane >> 3;                  // staging row-in-chunk 0..7
    const int sgr = (lane & 7) ^ srow;           // pre-swizzled source granule
    const bool ghi = (g >= 2);

#define STAGE_KV(buf, k0_)                                                               \
    {                                                                                    \
        _Pragma("unroll")                                                                \
        for (int it = 0; it < 2; ++it) {                                                 \
            const int ch = w * 2 + it;                                                   \
            const int row = ch * 8 + srow;                                               \
            GLOAD_LDS16(Kp + (size_t)((k0_) + row) * HEAD_W + sgr * 8,                   \
                        (unsigned short*)Kl[buf] + ch * 512);                            \
            GLOAD_LDS16(Vp + (size_t)row * T_SEQ + (k0_) + sgr * 8,                      \
                        (unsigned short*)Vl[buf] + ch * 512);                            \
        }                                                                                \
    }

    // Q fragments (B-operand): lane holds Q[q=qw+c][kb*32 + g*8 + j]
    short8 qf[2];
#pragma unroll
    for (int kb = 0; kb < 2; ++kb)
        qf[kb] = *(const short8*)(Qp + (size_t)(qw + c) * HEAD_W + kb * 32 + g * 8);

    f32x4 o[4];
#pragma unroll
    for (int i = 0; i < 4; ++i) o[i] = (f32x4){0.f, 0.f, 0.f, 0.f};
    float m = -1e30f, l = 0.f;     // per q-row (q = qw + c), replicated across g
    const float a16 = slope2 * 16.0f;
    float arl[4];
#pragma unroll
    for (int r = 0; r < 4; ++r) arl[r] = slope2 * (float)r;

    const int nt = q0 / 64 + 1;
    STAGE_KV((nt - 1) & 1, q0);
    __syncthreads();

    for (int t = nt - 1; t >= 0; --t) {
        const int k0 = t * 64;
        if (t > 0) STAGE_KV((t - 1) & 1, k0 - 64);   // in flight under compute
        const unsigned short* Kt = Kl[t & 1];
        const unsigned short* Vt = Vl[t & 1];

        // ---- S^T = K Q^T : lane (g,c) holds S[k = ct*16+g*4+r][q = c] ----
        f32x4 s[4];
#pragma unroll
        for (int ct = 0; ct < 4; ++ct) s[ct] = (f32x4){0.f, 0.f, 0.f, 0.f};
#pragma unroll
        for (int ct = 0; ct < 4; ++ct)
#pragma unroll
            for (int kb = 0; kb < 2; ++kb) {
                const short8 kf = *(const short8*)(Kt + (ct * 16 + c) * 64 +
                                                   (((kb * 4 + g) ^ (c & 7)) * 8));
                s[ct] = __builtin_amdgcn_mfma_f32_16x16x32_bf16(kf, qf[kb], s[ct], 0, 0, 0);
            }

        // ---- ALiBi (exp2 domain): s += slope2*(j - i), j = k0+ct*16+g*4+r, i = qw+c ----
        const float al0 = slope2 * (float)(k0 + g * 4 - qw - c);
#pragma unroll
        for (int ct = 0; ct < 4; ++ct) {
            const float act = al0 + a16 * (float)ct;
#pragma unroll
            for (int r = 0; r < 4; ++r) s[ct][r] += act + arl[r];
        }
        if (t == nt - 1) {   // diagonal tile: causal mask (j > i -> -inf)
            const int ri = w * 16 + c - g * 4;
#pragma unroll
            for (int ct = 0; ct < 4; ++ct)
#pragma unroll
                for (int r = 0; r < 4; ++r)
                    s[ct][r] = (ct * 16 + r > ri) ? -1e30f : s[ct][r];
        }

        // ---- row max (q = c): in-lane over 16 + 2 shuffles across g ----
        float tm = s[0][0];
#pragma unroll
        for (int ct = 0; ct < 4; ++ct)
#pragma unroll
            for (int r = 0; r < 4; ++r) tm = fmaxf(tm, s[ct][r]);
        tm = fmaxf(tm, __shfl_xor(tm, 16));
        tm = fmaxf(tm, __shfl_xor(tm, 32));

        // ---- defer-max: rescale only if some row's max grew past THR=8 ----
        if (!__all(tm <= m + 8.0f)) {
            const float mn = fmaxf(m, tm);
            const float sc = exp2f(m - mn);
            m = mn;
            l *= sc;
            float scr[4];
#pragma unroll
            for (int r = 0; r < 4; ++r) scr[r] = __shfl(sc, g * 4 + r);  // to output rows
#pragma unroll
            for (int db = 0; db < 4; ++db)
#pragma unroll
                for (int r = 0; r < 4; ++r) o[db][r] *= scr[r];
        }

        // ---- P = exp2(s - m), row sum ----
        float rs = 0.f;
#pragma unroll
        for (int ct = 0; ct < 4; ++ct)
#pragma unroll
            for (int r = 0; r < 4; ++r) {
                const float p = exp2f(s[ct][r] - m);
                s[ct][r] = p;
                rs += p;
            }
        rs += __shfl_xor(rs, 16);
        rs += __shfl_xor(rs, 32);
        l += rs;

        // ---- pack P to bf16 pairs: pk[ct][v] = (P[ct][2v], P[ct][2v+1]) ----
        uint32_t pk[4][2];
#pragma unroll
        for (int ct = 0; ct < 4; ++ct)
#pragma unroll
            for (int v = 0; v < 2; ++v)
                pk[ct][v] = cvt_pk_bf16(s[ct][2 * v], s[ct][2 * v + 1]);

        // ---- in-register redistribute to A-fragment layout + PV ----
#pragma unroll
        for (int kb = 0; kb < 2; ++kb) {
            uint32_t pu[4];
#pragma unroll
            for (int v = 0; v < 2; ++v) {
                const uint32_t s0v = ghi ? pk[2 * kb + 1][v] : pk[2 * kb][v];
                const uint32_t s1v = ghi ? pk[2 * kb][v]     : pk[2 * kb + 1][v];
                const uint32_t x16 = __shfl_xor(s0v, 16);
                const uint32_t x32 = __shfl_xor(s1v, 32);
                const uint32_t x48 = __shfl_xor(s1v, 48);
                pu[v]     = (g == 0) ? s0v : (g == 1) ? x48 : (g == 2) ? x32 : x16;
                pu[2 + v] = (g == 0) ? x16 : (g == 1) ? x32 : (g == 2) ? x48 : s0v;
            }
            union { uint32_t u[4]; short8 s8; } pa;
            pa.u[0] = pu[0]; pa.u[1] = pu[1]; pa.u[2] = pu[2]; pa.u[3] = pu[3];
#pragma unroll
            for (int db = 0; db < 4; ++db) {
                const short8 vf = *(const short8*)(Vt + (db * 16 + c) * 64 +
                                                   (((kb * 4 + g) ^ (c & 7)) * 8));
                o[db] = __builtin_amdgcn_mfma_f32_16x16x32_bf16(pa.s8, vf, o[db], 0, 0, 0);
            }
        }
        __syncthreads();   // drains next-tile staging + this-tile LDS reads
    }

    // ---- epilogue: o[db][r] = O[q = qw+g*4+r][d = db*16+c]; l is per q=c -> shuffle ----
    const float linv = 1.0f / l;
    float lr[4];
#pragma unroll
    for (int r = 0; r < 4; ++r) lr[r] = __shfl(linv, g * 4 + r);
#pragma unroll
    for (int db = 0; db < 4; ++db)
#pragma unroll
        for (int r = 0; r < 4; ++r)
            outp[((size_t)b * T_SEQ + qw + g * 4 + r) * D_MODEL + h * HEAD_W + db * 16 + c] =
                o[db][r] * lr[r];
#undef STAGE_KV
}

// ---------------- launch ----------------
extern "C" void kernel_launch(void* const* d_in, const int* in_sizes, int n_in,
                              void* d_out, int out_size, void* d_ws, size_t ws_size,
                              hipStream_t stream) {
    const float* x  = (const float*)d_in[0];
    // d_in[1] = additive causal mask, applied analytically -> unused
    const float* Wq = (const float*)d_in[2];
    const float* Wk = (const float*)d_in[3];
    const float* Wv = (const float*)d_in[4];
    float* out = (float*)d_out;

    uint8_t* ws = (uint8_t*)d_ws;
    unsigned short* xb  = (unsigned short*)(ws);              // 8 MB  x bf16 [4096,1024]
    unsigned short* wqb = (unsigned short*)(ws + 8388608);    // 2 MB  Wq * (log2e/8)
    unsigned short* wkb = (unsigned short*)(ws + 10485760);   // 2 MB
    unsigned short* wvb = (unsigned short*)(ws + 12582912);   // 2 MB
    unsigned short* Qb  = (unsigned short*)(ws + 14680064);   // 8 MB  [b,h,t,w]
    unsigned short* Kb  = (unsigned short*)(ws + 23068672);   // 8 MB  [b,h,t,w]
    unsigned short* Vtb = (unsigned short*)(ws + 31457280);   // 8 MB  [b,h,w,t]

    cvt_fused<<<7168, 256, 0, stream>>>((const float4*)x, (const float4*)Wq,
                                        (const float4*)Wk, (const float4*)Wv,
                                        (uint64_t*)xb, (uint64_t*)wqb,
                                        (uint64_t*)wkb, (uint64_t*)wvb);

    dim3 gg(D_MODEL / 128, (N_B * T_SEQ) / 128, 3);   // (8, 32, 3)
    qkv_gemm<<<gg, 256, 0, stream>>>(xb, wqb, wkb, wvb, Qb, Kb, Vtb);

    attn_fwd<<<1024, 256, 0, stream>>>(Qb, Kb, Vtb, out);
}